// Round 14
// baseline (241.958 us; speedup 1.0000x reference)
//
#include <hip/hip_runtime.h>
#include <stdint.h>

#define T_STEPS 256
#define F_IN 64
#define L2E 1.44269504f

typedef __bf16 bf16x8 __attribute__((ext_vector_type(8)));
typedef float f32x4 __attribute__((ext_vector_type(4)));
typedef uint32_t u32;
typedef uint32_t u32x4 __attribute__((ext_vector_type(4)));

#define GLDS16(gp, lp)                                                         \
    __builtin_amdgcn_global_load_lds(                                          \
        (const __attribute__((address_space(1))) unsigned int*)(gp),           \
        (__attribute__((address_space(3))) unsigned int*)(lp), 16, 0, 0)

static __device__ __forceinline__ u32 pk2(float lo, float hi) {
    unsigned short a = __builtin_bit_cast(unsigned short, (__bf16)lo);
    unsigned short b = __builtin_bit_cast(unsigned short, (__bf16)hi);
    return (u32)a | ((u32)b << 16);
}

// R13 base (1 wave = one 16-row tile, no barriers, no h-LDS, shuffle h-exchange,
// accx pipeline) with a rebuilt x-supply:
//  * each glds reads ONE ROW's next 4 steps: 64 lanes x 16B fully contiguous 1KB
//    (16 consecutive 64B lines) instead of 16 scattered lines across rows.
//  * 4-step groups, 2 slots/wave (16KB each, 128KB LDS/block), stage group G+2
//    while consuming G -> 16-32KB in flight per wave (was 8KB = depth 2).
//  * LDS chunk swizzle c ^= (row&7), applied on the global source per lane
//    (involution; reader applies the same XOR). ds_reads <=2-way (free).
// Layout: xg[wave][slot][row][sub 0..3][feature 0..63] floats; 16B chunk index
// c = sub*16 + fchunk; LDS holds global chunk (c ^ (row&7)) at slot c.
__global__ __launch_bounds__(256, 1)
void lstm_fused(const float* __restrict__ x,
                const float* __restrict__ Wl,   // [96][128]
                const float* __restrict__ bl,   // [128]
                const float* __restrict__ Wd,   // [32]
                const float* __restrict__ bd,   // [1]
                float* __restrict__ out)        // [B]
{
    __shared__ __align__(16) float xg[4][2][16][256];   // 128 KB

    const int lane = threadIdx.x & 63;
    const int wid  = threadIdx.x >> 6;
    const int cl   = lane & 15;
    const int g4   = lane >> 4;
    const int rowBase = blockIdx.x * 64 + wid * 16;

    // gate-type scale per tile q (q=0,1: i; 2,3: j; 4,5: f; 6,7: o)
#define GSC(q) (((q) >> 1) == 1 ? -2.0f * L2E : -L2E)

    // ---- 24 pre-scaled W^T A-fragments (standard K-row order, R13-proven) ----
    bf16x8 wfrag[3][8];
#pragma unroll
    for (int kc = 0; kc < 3; ++kc) {
#pragma unroll
        for (int q = 0; q < 8; ++q) {
            bf16x8 v;
#pragma unroll
            for (int j = 0; j < 8; ++j)
                v[j] = (__bf16)(GSC(q) * Wl[(kc * 32 + g4 * 8 + j) * 128 + q * 16 + cl]);
            wfrag[kc][q] = v;
        }
    }

    // ---- pre-scaled bias as MFMA C-init ----
    f32x4 biasf[8];
#pragma unroll
    for (int q = 0; q < 8; ++q) {
#pragma unroll
        for (int r = 0; r < 4; ++r) {
            const int gate = q * 16 + g4 * 4 + r;
            biasf[q][r] = GSC(q) * (bl[gate] + ((q >> 1) == 2 ? 1.0f : 0.0f));
        }
    }
    const float bd0 = bd[0];
    float wdl[4], wdh[4];
#pragma unroll
    for (int r = 0; r < 4; ++r) {
        wdl[r] = Wd[4 * g4 + r];
        wdh[r] = Wd[16 + 4 * g4 + r];
    }

    // ---- staging: per-lane XOR'd byte offsets (8 variants, one per row&7) ----
    const char* xbase = (const char*)(x + (size_t)rowBase * (size_t)(T_STEPS * F_IN));
    int loff[8];
#pragma unroll
    for (int k = 0; k < 8; ++k) loff[k] = ((lane ^ k) << 4);

    asm volatile("s_waitcnt vmcnt(0)" ::: "memory");   // drain setup loads: exact counting
    __builtin_amdgcn_sched_barrier(0);

    // one glds per row: 1KB contiguous = steps [4G..4G+4) x 64 features of row r
#define STAGE_GROUP(G, SL) do {                                                \
    _Pragma("unroll")                                                          \
    for (int r = 0; r < 16; ++r) {                                             \
        const char* gp = xbase + (size_t)r * (size_t)(T_STEPS * F_IN * 4)      \
                       + (size_t)(G) * 1024 + loff[r & 7];                     \
        GLDS16(gp, &xg[wid][SL][r][0]);                                        \
    }                                                                          \
} while (0)

    STAGE_GROUP(0, 0);
    STAGE_GROUP(1, 1);

    // shuffle-exchange constants (R13-proven)
    const int srcA = cl + 32 * (g4 & 1);
    const int srcB = srcA + 16;
    const int sel  = g4 >> 1;
    const int kswz = cl & 7;

    f32x4 csl = {0.f, 0.f, 0.f, 0.f};   // c' = -2*L2E*c, units 4g4+r
    f32x4 csh = {0.f, 0.f, 0.f, 0.f};   // units 16+4g4+r
    f32x4 hlv, hhv;
    u32x4 ahw = {0u, 0u, 0u, 0u};       // h0 = 0
    f32x4 accx[8];

#define CELL(AI, AJ, AF, AO, CS, HV) do {                                      \
    _Pragma("unroll")                                                          \
    for (int r = 0; r < 4; ++r) {                                              \
        float I  = __builtin_amdgcn_exp2f((AI)[r]);                            \
        float J  = __builtin_amdgcn_exp2f((AJ)[r]);                            \
        float Fv = __builtin_amdgcn_exp2f((AF)[r]);                            \
        float O  = __builtin_amdgcn_exp2f((AO)[r]);                            \
        float t3 = (1.0f + I) * (1.0f + J);                                    \
        float uu = 1.0f + Fv;                                                  \
        float np = __builtin_fmaf(J, 2.0f * L2E, -2.0f * L2E);                 \
        float r1 = __builtin_amdgcn_rcpf(t3 * uu);                             \
        float nm = __builtin_fmaf((CS)[r], t3, np * uu);                       \
        float cp = nm * r1;                                                    \
        float C  = __builtin_amdgcn_exp2f(cp);                                 \
        float r2 = __builtin_amdgcn_rcpf((1.0f + C) * (1.0f + O));             \
        (HV)[r] = (1.0f - C) * r2;                                             \
        (CS)[r] = cp;                                                          \
    }                                                                          \
} while (0)

    // x-gate precompute for step TT: read row cl's chunks (swizzled), 8 MFMAs.
    // gc0 = (TT&3)*16 + 2*g4 (even) -> LDS chunks gc0^kswz, ^1, ^8, ^8^1.
#define XGATES(TT) do {                                                        \
    const float* base = &xg[wid][((TT) >> 2) & 1][cl][0];                      \
    const int c00 = (((TT) & 3) * 16 + 2 * g4) ^ kswz;                         \
    f32x4 xr0 = *(const f32x4*)(base + (size_t)( c00          ) * 4);          \
    f32x4 xr1 = *(const f32x4*)(base + (size_t)( c00 ^ 1      ) * 4);          \
    f32x4 xr2 = *(const f32x4*)(base + (size_t)( c00 ^ 8      ) * 4);          \
    f32x4 xr3 = *(const f32x4*)(base + (size_t)((c00 ^ 8) ^ 1 ) * 4);          \
    bf16x8 ax0, ax1;                                                           \
    _Pragma("unroll")                                                          \
    for (int j = 0; j < 4; ++j) {                                              \
        ax0[j]     = (__bf16)xr0[j];                                           \
        ax0[4 + j] = (__bf16)xr1[j];                                           \
        ax1[j]     = (__bf16)xr2[j];                                           \
        ax1[4 + j] = (__bf16)xr3[j];                                           \
    }                                                                          \
    _Pragma("unroll")                                                          \
    for (int q = 0; q < 8; ++q) {                                              \
        f32x4 a = __builtin_amdgcn_mfma_f32_16x16x32_bf16(wfrag[0][q], ax0, biasf[q], 0, 0, 0); \
        accx[q] = __builtin_amdgcn_mfma_f32_16x16x32_bf16(wfrag[1][q], ax1, a, 0, 0, 0);        \
    }                                                                          \
} while (0)

    // critical chain for one step: h-MFMA on accx, cell, pack, shuffle-exchange
#define CHAIN() do {                                                           \
    bf16x8 ah = __builtin_bit_cast(bf16x8, ahw);                               \
    f32x4 acc[8];                                                              \
    _Pragma("unroll")                                                          \
    for (int q = 0; q < 8; ++q)                                                \
        acc[q] = __builtin_amdgcn_mfma_f32_16x16x32_bf16(wfrag[2][q], ah, accx[q], 0, 0, 0); \
    CELL(acc[0], acc[2], acc[4], acc[6], csl, hlv);                            \
    CELL(acc[1], acc[3], acc[5], acc[7], csh, hhv);                            \
    u32 W0 = pk2(hlv[0], hlv[1]);                                              \
    u32 W1 = pk2(hlv[2], hlv[3]);                                              \
    u32 W2 = pk2(hhv[0], hhv[1]);                                              \
    u32 W3 = pk2(hhv[2], hhv[3]);                                              \
    int A0 = __shfl((int)W0, srcA, 64), A1 = __shfl((int)W1, srcA, 64);        \
    int A2 = __shfl((int)W2, srcA, 64), A3 = __shfl((int)W3, srcA, 64);        \
    int B0 = __shfl((int)W0, srcB, 64), B1 = __shfl((int)W1, srcB, 64);        \
    int B2 = __shfl((int)W2, srcB, 64), B3 = __shfl((int)W3, srcB, 64);        \
    ahw[0] = (u32)(sel ? A2 : A0);                                             \
    ahw[1] = (u32)(sel ? A3 : A1);                                             \
    ahw[2] = (u32)(sel ? B2 : B0);                                             \
    ahw[3] = (u32)(sel ? B3 : B1);                                             \
} while (0)

    asm volatile("s_waitcnt vmcnt(16)" ::: "memory");   // group 0 landed (32 -> 16)
    __builtin_amdgcn_sched_barrier(0);
    XGATES(0);

    for (int G = 0; G < 64; ++G) {
        const int t0 = 4 * G;
        CHAIN(); XGATES(t0 + 1);
        CHAIN(); XGATES(t0 + 2);
        CHAIN(); XGATES(t0 + 3);
        CHAIN();
        if (G < 62) {
            STAGE_GROUP(G + 2, G & 1);                   // into just-freed slot
            asm volatile("s_waitcnt vmcnt(16)" ::: "memory");  // group G+1 landed
        } else {
            asm volatile("s_waitcnt vmcnt(0)" ::: "memory");   // tail drain
        }
        __builtin_amdgcn_sched_barrier(0);
        const int tn = (t0 + 4 < T_STEPS) ? t0 + 4 : T_STEPS - 1;
        XGATES(tn);                                      // dead work on last group
    }
#undef CHAIN
#undef XGATES
#undef CELL
#undef STAGE_GROUP

    asm volatile("s_waitcnt vmcnt(0)" ::: "memory");

    // ---- epilogue: out[b] = ELU(sum_u h[u]*Wd[u] + bd) ----
    float v = 0.f;
#pragma unroll
    for (int r = 0; r < 4; ++r) {
        v = __builtin_fmaf(hlv[r], wdl[r], v);
        v = __builtin_fmaf(hhv[r], wdh[r], v);
    }
    v += __shfl_xor(v, 16, 64);
    v += __shfl_xor(v, 32, 64);
    if (lane < 16) {
        float z = v + bd0;
        out[rowBase + lane] = z > 0.f ? z : (__expf(z) - 1.0f);
    }
}

extern "C" void kernel_launch(void* const* d_in, const int* in_sizes, int n_in,
                              void* d_out, int out_size, void* d_ws, size_t ws_size,
                              hipStream_t stream) {
    const float* x  = (const float*)d_in[0];
    const float* Wl = (const float*)d_in[1];
    const float* bl = (const float*)d_in[2];
    const float* Wd = (const float*)d_in[3];
    const float* bd = (const float*)d_in[4];
    float* out = (float*)d_out;

    const int rows = out_size;              // B = 16384
    const int grid = (rows + 63) / 64;      // 64 rows per 256-thread block (4 waves x 16)
    hipLaunchKernelGGL(lstm_fused, dim3(grid), dim3(256), 0, stream,
                       x, Wl, bl, Wd, bd, out);
}